// Round 1
// baseline (236.394 us; speedup 1.0000x reference)
//
#include <hip/hip_runtime.h>
#include <math.h>

// Problem constants (fixed by setup_inputs): [B=2, 1, D=192, H=192, W=192] fp32
#define W 192
#define H 192
#define DEPTH 192
#define BATCH 2
#define TW 32          // tile width  (threads x)
#define TH 8           // tile height (threads y)
#define DC 48          // D-planes per block chunk
#define HW (H * W)
#define VOL ((size_t)DEPTH * HW)

// Separable Sobel: s=[1,2,1], d=[-1,0,1] (signs irrelevant — magnitudes squared).
// Per plane p we compute, for each input:
//   dx_s = s(H) d(W),  dy_s = d(H) s(W)'s H-combine deferred? No:
//   dx_s(p) = sum_h s * (x[w+1]-x[w-1])      (needs smooth over D later)
//   sxy (p) = s(H) s(W) smoothed plane       (z-gradient = sxy(p-1)-sxy(p+1))
//   dy_s(p) = rowsum(h-1) - rowsum(h+1)      (needs smooth over D later)
// Output at plane p-1 once planes p-2,p-1,p are in the rolling buffer.

__global__ __launch_bounds__(256) void sobel_loss_part(
    const float* __restrict__ pred, const float* __restrict__ gt,
    const float* __restrict__ mask, float* __restrict__ partials)
{
    __shared__ float2 tile[TH + 2][TW + 2];   // .x = pred, .y = gt

    const int tid = threadIdx.x;
    const int lw  = tid & 31;
    const int lh  = tid >> 5;
    const int tileIdx = blockIdx.x;                 // 0..143
    const int w0 = (tileIdx % (W / TW)) * TW;
    const int h0 = (tileIdx / (W / TW)) * TH;
    const int d0 = blockIdx.y * DC;
    const size_t base = (size_t)blockIdx.z * VOL;
    const int gw = w0 + lw, gh = h0 + lh;

    // rolling buffers (index 0 = oldest plane p-2, 2 = newest plane p)
    float adx0=0,adx1=0,adx2=0, ady0=0,ady1=0,ady2=0, as0=0,as1=0,as2=0;
    float bdx0=0,bdx1=0,bdx2=0, bdy0=0,bdy1=0,bdy2=0, bs0=0,bs1=0,bs2=0;
    float ac1=0, ac2=0, bc1=0, bc2=0;   // center values (only middle needed)
    float acc = 0.f;

    for (int p = d0 - 1; p <= d0 + DC; ++p) {
        float adx=0.f, ady=0.f, asx=0.f, ac=0.f;
        float bdx=0.f, bdy=0.f, bsx=0.f, bc=0.f;
        if (p >= 0 && p < DEPTH) {                 // uniform branch across block
            __syncthreads();                       // protect prior-plane reads
            const size_t pbase = base + (size_t)p * HW;
            #pragma unroll
            for (int i = tid; i < (TH + 2) * (TW + 2); i += 256) {
                int r = i / (TW + 2), c = i - r * (TW + 2);
                int yh = h0 - 1 + r, xw = w0 - 1 + c;
                float va = 0.f, vb = 0.f;
                if ((unsigned)yh < (unsigned)H && (unsigned)xw < (unsigned)W) {
                    size_t idx = pbase + (size_t)yh * W + xw;
                    va = pred[idx];
                    vb = gt[idx];
                }
                tile[r][c] = make_float2(va, vb);
            }
            __syncthreads();

            float2 r0a = tile[lh    ][lw], r0b = tile[lh    ][lw + 1], r0c = tile[lh    ][lw + 2];
            float2 r1a = tile[lh + 1][lw], r1b = tile[lh + 1][lw + 1], r1c = tile[lh + 1][lw + 2];
            float2 r2a = tile[lh + 2][lw], r2b = tile[lh + 2][lw + 1], r2c = tile[lh + 2][lw + 2];

            // pred
            float s0 = r0a.x + 2.f * r0b.x + r0c.x, dd0 = r0c.x - r0a.x;
            float s1 = r1a.x + 2.f * r1b.x + r1c.x, dd1 = r1c.x - r1a.x;
            float s2 = r2a.x + 2.f * r2b.x + r2c.x, dd2 = r2c.x - r2a.x;
            adx = dd0 + 2.f * dd1 + dd2;
            asx = s0 + 2.f * s1 + s2;
            ady = s0 - s2;
            ac  = r1b.x;
            // gt
            s0 = r0a.y + 2.f * r0b.y + r0c.y; dd0 = r0c.y - r0a.y;
            s1 = r1a.y + 2.f * r1b.y + r1c.y; dd1 = r1c.y - r1a.y;
            s2 = r2a.y + 2.f * r2b.y + r2c.y; dd2 = r2c.y - r2a.y;
            bdx = dd0 + 2.f * dd1 + dd2;
            bsx = s0 + 2.f * s1 + s2;
            bdy = s0 - s2;
            bc  = r1b.y;
        }

        // shift rolling buffers
        adx0 = adx1; adx1 = adx2; adx2 = adx;
        ady0 = ady1; ady1 = ady2; ady2 = ady;
        as0  = as1;  as1  = as2;  as2  = asx;
        bdx0 = bdx1; bdx1 = bdx2; bdx2 = bdx;
        bdy0 = bdy1; bdy1 = bdy2; bdy2 = bdy;
        bs0  = bs1;  bs1  = bs2;  bs2  = bsx;
        float acm = ac1; ac1 = ac2; ac2 = ac;
        float bcm = bc1; bc1 = bc2; bc2 = bc;

        if (p >= d0 + 1) {
            int od = p - 1;  // output plane
            float gxa = adx0 + 2.f * adx1 + adx2;
            float gya = ady0 + 2.f * ady1 + ady2;
            float gza = as0 - as2;
            float gxb = bdx0 + 2.f * bdx1 + bdx2;
            float gyb = bdy0 + 2.f * bdy1 + bdy2;
            float gzb = bs0 - bs2;
            float ga = sqrtf(gxa * gxa + gya * gya + gza * gza + 1e-10f);
            float gb = sqrtf(gxb * gxb + gyb * gyb + gzb * gzb + 1e-10f);
            float m  = mask[base + (size_t)od * HW + (size_t)gh * W + gw];
            float dm = acm - bcm;           // pred - gt at center, plane od
            float mse = dm * dm * m;
            float dg  = gb - ga;
            float mge = dg * dg * m;
            acc += mse * (1.f + tanhf(mge));
        }
    }

    // block reduction: wave64 shuffle, then 4 wave partials via LDS
    float v = acc;
    #pragma unroll
    for (int o = 32; o > 0; o >>= 1) v += __shfl_down(v, o, 64);
    __shared__ float red[4];
    if ((tid & 63) == 0) red[tid >> 6] = v;
    __syncthreads();
    if (tid == 0) {
        float s = red[0] + red[1] + red[2] + red[3];
        partials[(size_t)blockIdx.z * (gridDim.x * gridDim.y)
                 + (size_t)blockIdx.y * gridDim.x + blockIdx.x] = s;
    }
}

__global__ __launch_bounds__(256) void reduce_final(
    const float* __restrict__ partials, int n, float* __restrict__ out)
{
    int tid = threadIdx.x;
    double s = 0.0;
    for (int i = tid; i < n; i += 256) s += (double)partials[i];
    #pragma unroll
    for (int o = 32; o > 0; o >>= 1) s += __shfl_down(s, o, 64);
    __shared__ double red[4];
    if ((tid & 63) == 0) red[tid >> 6] = s;
    __syncthreads();
    if (tid == 0) {
        double t = red[0] + red[1] + red[2] + red[3];
        const double ntot = (double)BATCH * (double)DEPTH * (double)H * (double)W;
        out[0] = (float)(t / ntot);
    }
}

extern "C" void kernel_launch(void* const* d_in, const int* in_sizes, int n_in,
                              void* d_out, int out_size, void* d_ws, size_t ws_size,
                              hipStream_t stream) {
    const float* pred = (const float*)d_in[0];
    const float* gt   = (const float*)d_in[1];
    const float* mask = (const float*)d_in[2];
    float* partials = (float*)d_ws;

    dim3 grid((W / TW) * (H / TH), DEPTH / DC, BATCH);   // 144 x 4 x 2 = 1152
    sobel_loss_part<<<grid, 256, 0, stream>>>(pred, gt, mask, partials);

    int nparts = grid.x * grid.y * grid.z;
    reduce_final<<<1, 256, 0, stream>>>(partials, nparts, (float*)d_out);
}

// Round 2
// 228.424 us; speedup vs baseline: 1.0349x; 1.0349x over previous
//
#include <hip/hip_runtime.h>
#include <math.h>

// Problem constants (fixed by setup_inputs): [B=2, 1, D=192, H=192, W=192] fp32
#define W 192
#define H 192
#define DEPTH 192
#define BATCH 2
#define TW 32          // tile width  (threads x)
#define TH 8           // tile height (threads y)
#define DC 24          // D-planes per block chunk (24 -> 2304 blocks, ~full occupancy)
#define HW (H * W)
#define VOL ((size_t)DEPTH * HW)
#define HALO_N ((TH + 2) * (TW + 2))   // 340 halo elements per plane

// Separable Sobel: s=[1,2,1], d=[-1,0,1] (signs irrelevant — magnitudes squared).
// Per plane p, per input:
//   adx(p) = s_h d_w x   asx(p) = s_h s_w x   ady(p) = d_h s_w x
// Then roll over D: gx = s_d(adx), gy = s_d(ady), gz = d_d(asx).
// Two planes staged per barrier pair to halve barrier count.

__global__ __launch_bounds__(256) void sobel_loss_part(
    const float* __restrict__ pred, const float* __restrict__ gt,
    const float* __restrict__ mask, float* __restrict__ partials)
{
    __shared__ float2 tile[2][HALO_N];   // .x = pred, .y = gt

    const int tid = threadIdx.x;
    const int lw  = tid & 31;
    const int lh  = tid >> 5;
    const int tileIdx = blockIdx.x;                 // 0..143
    const int w0 = (tileIdx % (W / TW)) * TW;
    const int h0 = (tileIdx / (W / TW)) * TH;
    const int d0 = blockIdx.y * DC;
    const size_t base = (size_t)blockIdx.z * VOL;
    const int gw = w0 + lw, gh = h0 + lh;

    // ---- hoisted staging geometry (loop-invariant over D) ----
    const int i0 = tid;                 // always < 340
    const int i1 = tid + 256;           // valid iff tid < 84
    const int r0i = i0 / (TW + 2), c0i = i0 - r0i * (TW + 2);
    const int r1i = i1 / (TW + 2), c1i = i1 - r1i * (TW + 2);
    const int y0 = h0 - 1 + r0i, x0 = w0 - 1 + c0i;
    const int y1 = h0 - 1 + r1i, x1 = w0 - 1 + c1i;
    const bool in0 = ((unsigned)y0 < (unsigned)H) && ((unsigned)x0 < (unsigned)W);
    const bool wr1 = (i1 < HALO_N);
    const bool in1 = wr1 && ((unsigned)y1 < (unsigned)H) && ((unsigned)x1 < (unsigned)W);
    const size_t off0 = in0 ? ((size_t)y0 * W + x0) : 0;
    const size_t off1 = in1 ? ((size_t)y1 * W + x1) : 0;

    // rolling buffers (0 = oldest plane p-2, 2 = newest plane p)
    float adx0=0,adx1=0,adx2=0, ady0=0,ady1=0,ady2=0, as0=0,as1=0,as2=0;
    float bdx0=0,bdx1=0,bdx2=0, bdy0=0,bdy1=0,bdy2=0, bs0=0,bs1=0,bs2=0;
    float ac1=0, ac2=0, bc1=0, bc2=0;   // center values
    float acc = 0.f;

    const int rb = lh * (TW + 2) + lw;  // stencil read base in flat tile

    // planes d0-1 .. d0+DC  (DC+2 = 26 planes = 13 pairs)
    for (int s = 0; s < (DC + 2) / 2; ++s) {
        const int p0 = d0 - 1 + 2 * s;
        const int p1 = p0 + 1;
        const bool v0 = (p0 >= 0) && (p0 < DEPTH);   // block-uniform
        const bool v1 = (p1 < DEPTH);

        __syncthreads();   // previous pair's reads complete before overwrite
        {
            const size_t pb0 = base + (size_t)p0 * HW;
            const size_t pb1 = base + (size_t)p1 * HW;
            float a, b;
            a = (v0 && in0) ? pred[pb0 + off0] : 0.f;
            b = (v0 && in0) ? gt  [pb0 + off0] : 0.f;
            tile[0][i0] = make_float2(a, b);
            a = (v1 && in0) ? pred[pb1 + off0] : 0.f;
            b = (v1 && in0) ? gt  [pb1 + off0] : 0.f;
            tile[1][i0] = make_float2(a, b);
            if (wr1) {
                a = (v0 && in1) ? pred[pb0 + off1] : 0.f;
                b = (v0 && in1) ? gt  [pb0 + off1] : 0.f;
                tile[0][i1] = make_float2(a, b);
                a = (v1 && in1) ? pred[pb1 + off1] : 0.f;
                b = (v1 && in1) ? gt  [pb1 + off1] : 0.f;
                tile[1][i1] = make_float2(a, b);
            }
        }
        __syncthreads();

        #pragma unroll
        for (int q = 0; q < 2; ++q) {
            const int p = p0 + q;
            const float2* T = tile[q];
            float2 r0a = T[rb],      r0b = T[rb + 1],      r0c = T[rb + 2];
            float2 r1a = T[rb + 34], r1b = T[rb + 35],     r1c = T[rb + 36];
            float2 r2a = T[rb + 68], r2b = T[rb + 69],     r2c = T[rb + 70];

            // pred
            float s0 = r0a.x + 2.f * r0b.x + r0c.x, dd0 = r0c.x - r0a.x;
            float s1 = r1a.x + 2.f * r1b.x + r1c.x, dd1 = r1c.x - r1a.x;
            float s2 = r2a.x + 2.f * r2b.x + r2c.x, dd2 = r2c.x - r2a.x;
            float adx = dd0 + 2.f * dd1 + dd2;
            float asx = s0 + 2.f * s1 + s2;
            float ady = s0 - s2;
            float ac  = r1b.x;
            // gt
            s0 = r0a.y + 2.f * r0b.y + r0c.y; dd0 = r0c.y - r0a.y;
            s1 = r1a.y + 2.f * r1b.y + r1c.y; dd1 = r1c.y - r1a.y;
            s2 = r2a.y + 2.f * r2b.y + r2c.y; dd2 = r2c.y - r2a.y;
            float bdx = dd0 + 2.f * dd1 + dd2;
            float bsx = s0 + 2.f * s1 + s2;
            float bdy = s0 - s2;
            float bc  = r1b.y;

            // shift rolling buffers
            adx0 = adx1; adx1 = adx2; adx2 = adx;
            ady0 = ady1; ady1 = ady2; ady2 = ady;
            as0  = as1;  as1  = as2;  as2  = asx;
            bdx0 = bdx1; bdx1 = bdx2; bdx2 = bdx;
            bdy0 = bdy1; bdy1 = bdy2; bdy2 = bdy;
            bs0  = bs1;  bs1  = bs2;  bs2  = bsx;
            float acm = ac1; ac1 = ac2; ac2 = ac;
            float bcm = bc1; bc1 = bc2; bc2 = bc;

            if (p >= d0 + 1) {
                const int od = p - 1;  // output plane, d0 .. d0+DC-1
                float gxa = adx0 + 2.f * adx1 + adx2;
                float gya = ady0 + 2.f * ady1 + ady2;
                float gza = as0 - as2;
                float gxb = bdx0 + 2.f * bdx1 + bdx2;
                float gyb = bdy0 + 2.f * bdy1 + bdy2;
                float gzb = bs0 - bs2;
                float ga = __builtin_amdgcn_sqrtf(gxa * gxa + gya * gya + gza * gza + 1e-10f);
                float gb = __builtin_amdgcn_sqrtf(gxb * gxb + gyb * gyb + gzb * gzb + 1e-10f);
                float m  = mask[base + (size_t)od * HW + (size_t)gh * W + gw];
                float dm = acm - bcm;
                float mse = dm * dm * m;
                float dg  = gb - ga;
                float mge = dg * dg * m;
                // tanh(x) = 1 - 2/(e^{2x}+1); x >= 0 here, saturates via inf -> rcp=0
                float e = __expf(2.f * mge);
                float t = 1.f - 2.f * __builtin_amdgcn_rcpf(e + 1.f);
                acc += mse * (1.f + t);
            }
        }
    }

    // block reduction: wave64 shuffle, then 4 wave partials via LDS
    float v = acc;
    #pragma unroll
    for (int o = 32; o > 0; o >>= 1) v += __shfl_down(v, o, 64);
    __shared__ float red[4];
    if ((tid & 63) == 0) red[tid >> 6] = v;
    __syncthreads();
    if (tid == 0) {
        float s = red[0] + red[1] + red[2] + red[3];
        partials[(size_t)blockIdx.z * (gridDim.x * gridDim.y)
                 + (size_t)blockIdx.y * gridDim.x + blockIdx.x] = s;
    }
}

__global__ __launch_bounds__(256) void reduce_final(
    const float* __restrict__ partials, int n, float* __restrict__ out)
{
    int tid = threadIdx.x;
    double s = 0.0;
    for (int i = tid; i < n; i += 256) s += (double)partials[i];
    #pragma unroll
    for (int o = 32; o > 0; o >>= 1) s += __shfl_down(s, o, 64);
    __shared__ double red[4];
    if ((tid & 63) == 0) red[tid >> 6] = s;
    __syncthreads();
    if (tid == 0) {
        double t = red[0] + red[1] + red[2] + red[3];
        const double ntot = (double)BATCH * (double)DEPTH * (double)H * (double)W;
        out[0] = (float)(t / ntot);
    }
}

extern "C" void kernel_launch(void* const* d_in, const int* in_sizes, int n_in,
                              void* d_out, int out_size, void* d_ws, size_t ws_size,
                              hipStream_t stream) {
    const float* pred = (const float*)d_in[0];
    const float* gt   = (const float*)d_in[1];
    const float* mask = (const float*)d_in[2];
    float* partials = (float*)d_ws;

    dim3 grid((W / TW) * (H / TH), DEPTH / DC, BATCH);   // 144 x 8 x 2 = 2304
    sobel_loss_part<<<grid, 256, 0, stream>>>(pred, gt, mask, partials);

    int nparts = grid.x * grid.y * grid.z;
    reduce_final<<<1, 256, 0, stream>>>(partials, nparts, (float*)d_out);
}

// Round 3
// 185.565 us; speedup vs baseline: 1.2739x; 1.2310x over previous
//
#include <hip/hip_runtime.h>
#include <math.h>

// [B=2, 1, D=192, H=192, W=192] fp32
#define W 192
#define H 192
#define DEPTH 192
#define BATCH 2
#define TW 64          // tile width
#define TH 8           // tile height
#define DC 12          // output planes per block -> grid 72*16*2 = 2304 blocks
#define HW (H * W)
#define VOL ((size_t)DEPTH * HW)
#define LROW 72        // LDS row stride (floats), = aligned halo row [w0-4, w0+68)
#define LPLANE (LROW * 10)
#define NPAIR ((DC + 2) / 2)      // 7 pairs of planes: d0-1 .. d0+12
#define NITEM 720                 // float4 staging items per pair: 2 arrays * 2 planes * 10 rows * 18

__global__ __launch_bounds__(256) void sobel_loss_part(
    const float* __restrict__ pred, const float* __restrict__ gt,
    const float* __restrict__ mask, float* __restrict__ partials)
{
    __shared__ __align__(16) float lds[2 * 2 * LPLANE];   // [array][planeq][10 rows * 72]

    const int tid = threadIdx.x;
    const int tx = blockIdx.x % 3;          // W tile (0..2)
    const int ty = blockIdx.x / 3;          // H tile (0..23)
    const int w0 = tx * TW, h0 = ty * TH;
    const int d0 = blockIdx.y * DC;
    const size_t base = (size_t)blockIdx.z * VOL;

    // compute-thread geometry: 2 horizontally-adjacent outputs per thread
    const int wy  = tid >> 5;               // row 0..7
    const int wxo = (tid & 31) << 1;        // col 0,2,..,62
    const size_t moff = base + (size_t)(h0 + wy) * W + (w0 + wxo);  // + od*HW

    // ---- staging geometry (3 float4 items/thread, loop-invariant) ----
    // j = tid + 256k < 720: a=j/360 (0=pred,1=gt), q=plane in pair, r=row 0..9, c=col4 0..17
    int it_ok[3], it_st[3], it_q[3], it_lds[3];
    size_t it_goff[3];
    const float* it_src[3];
    #pragma unroll
    for (int k = 0; k < 3; ++k) {
        int j = tid + 256 * k;
        int jj = (j < NITEM) ? j : 0;
        int a = jj / 360; int pj = jj - a * 360;
        int q = pj / 180; int e = pj - q * 180;
        int r = e / 18;   int c = e - r * 18;
        int y  = h0 - 1 + r;
        int xf = w0 - 4 + 4 * c;            // 16B aligned; OOB float4s are fully OOB
        it_st[k]  = (j < NITEM);
        it_ok[k]  = it_st[k] && ((unsigned)y < (unsigned)H) && ((unsigned)xf < (unsigned)W);
        it_goff[k] = it_ok[k] ? ((size_t)y * W + xf) : 0;
        it_lds[k]  = ((a * 2 + q) * 10 + r) * LROW + 4 * c;
        it_q[k]    = q;
        it_src[k]  = a ? gt : pred;
    }

    float4 R[3];
    auto load_pair = [&](int s) {
        const int p0 = d0 - 1 + 2 * s;
        #pragma unroll
        for (int k = 0; k < 3; ++k) {
            const int p = p0 + it_q[k];
            const bool v = it_ok[k] && (p >= 0) && (p < DEPTH);
            R[k] = v ? *(const float4*)(it_src[k] + base + (size_t)p * HW + it_goff[k])
                     : make_float4(0.f, 0.f, 0.f, 0.f);
        }
    };

    float2 Mn = make_float2(0.f, 0.f), Mn1 = make_float2(0.f, 0.f);
    float2 Mc, Mc1;
    auto load_mask = [&](int s) {   // masks for round s outputs: planes d0+2s-2, d0+2s-1
        Mn  = *(const float2*)(mask + moff + (size_t)(d0 + 2 * s - 2) * HW);
        Mn1 = *(const float2*)(mask + moff + (size_t)(d0 + 2 * s - 1) * HW);
    };

    // rolling state: [array][output][age]; ct post-shift: [1]=c(p), [0]=c(p-1)
    float dx[2][2][3], dy[2][2][3], sm[2][2][3], ct[2][2][2];
    #pragma unroll
    for (int a = 0; a < 2; ++a)
        #pragma unroll
        for (int o = 0; o < 2; ++o) {
            dx[a][o][0]=dx[a][o][1]=dx[a][o][2]=0.f;
            dy[a][o][0]=dy[a][o][1]=dy[a][o][2]=0.f;
            sm[a][o][0]=sm[a][o][1]=sm[a][o][2]=0.f;
            ct[a][o][0]=ct[a][o][1]=0.f;
        }
    float acc = 0.f;

    load_pair(0);   // prefetch pair 0

    for (int s = 0; s < NPAIR; ++s) {
        __syncthreads();                    // previous round's LDS reads complete
        #pragma unroll
        for (int k = 0; k < 3; ++k)
            if (it_st[k]) *(float4*)(lds + it_lds[k]) = R[k];
        __syncthreads();

        Mc = Mn; Mc1 = Mn1;
        if (s + 1 < NPAIR) {
            load_pair(s + 1);               // issue next pair's loads (no wait)
            load_mask(s + 1);               // masks for round s+1 outputs
        }

        #pragma unroll
        for (int q = 0; q < 2; ++q) {
            const int p = d0 - 1 + 2 * s + q;
            float e[2][3][4];
            #pragma unroll
            for (int a = 0; a < 2; ++a)
                #pragma unroll
                for (int r = 0; r < 3; ++r)
                    #pragma unroll
                    for (int c = 0; c < 4; ++c)
                        e[a][r][c] = lds[(a * 2 + q) * LPLANE + (wy + r) * LROW + wxo + 3 + c];

            #pragma unroll
            for (int a = 0; a < 2; ++a)
                #pragma unroll
                for (int o = 0; o < 2; ++o) {
                    float s0 = e[a][0][o] + 2.f * e[a][0][o+1] + e[a][0][o+2];
                    float s1 = e[a][1][o] + 2.f * e[a][1][o+1] + e[a][1][o+2];
                    float s2 = e[a][2][o] + 2.f * e[a][2][o+1] + e[a][2][o+2];
                    float dd0 = e[a][0][o+2] - e[a][0][o];
                    float dd1 = e[a][1][o+2] - e[a][1][o];
                    float dd2 = e[a][2][o+2] - e[a][2][o];
                    dx[a][o][0] = dx[a][o][1]; dx[a][o][1] = dx[a][o][2]; dx[a][o][2] = dd0 + 2.f * dd1 + dd2;
                    sm[a][o][0] = sm[a][o][1]; sm[a][o][1] = sm[a][o][2]; sm[a][o][2] = s0 + 2.f * s1 + s2;
                    dy[a][o][0] = dy[a][o][1]; dy[a][o][1] = dy[a][o][2]; dy[a][o][2] = s0 - s2;
                    ct[a][o][0] = ct[a][o][1]; ct[a][o][1] = e[a][1][o+1];
                }

            if (p >= d0 + 1) {              // output plane od = p-1; ct[..][0] = c(p-1)
                const float2 M = q ? Mc1 : Mc;
                #pragma unroll
                for (int o = 0; o < 2; ++o) {
                    float gxa = dx[0][o][0] + 2.f * dx[0][o][1] + dx[0][o][2];
                    float gya = dy[0][o][0] + 2.f * dy[0][o][1] + dy[0][o][2];
                    float gza = sm[0][o][0] - sm[0][o][2];
                    float gxb = dx[1][o][0] + 2.f * dx[1][o][1] + dx[1][o][2];
                    float gyb = dy[1][o][0] + 2.f * dy[1][o][1] + dy[1][o][2];
                    float gzb = sm[1][o][0] - sm[1][o][2];
                    float ga = __builtin_amdgcn_sqrtf(gxa * gxa + gya * gya + gza * gza + 1e-10f);
                    float gb = __builtin_amdgcn_sqrtf(gxb * gxb + gyb * gyb + gzb * gzb + 1e-10f);
                    float m  = o ? M.y : M.x;
                    float dm = ct[0][o][0] - ct[1][o][0];
                    float mse = dm * dm * m;
                    float dg  = gb - ga;
                    float mge = dg * dg * m;
                    // tanh(x) = 1 - 2/(e^{2x}+1), x >= 0; saturates via inf -> rcp -> 0
                    float ex = __expf(2.f * mge);
                    float t  = 1.f - 2.f * __builtin_amdgcn_rcpf(ex + 1.f);
                    acc += mse * (1.f + t);
                }
            }
        }
    }

    // block reduction
    float v = acc;
    #pragma unroll
    for (int o = 32; o > 0; o >>= 1) v += __shfl_down(v, o, 64);
    __shared__ float red[4];
    if ((tid & 63) == 0) red[tid >> 6] = v;
    __syncthreads();
    if (tid == 0) {
        partials[(size_t)blockIdx.z * (gridDim.x * gridDim.y)
                 + (size_t)blockIdx.y * gridDim.x + blockIdx.x]
            = red[0] + red[1] + red[2] + red[3];
    }
}

__global__ __launch_bounds__(256) void reduce_final(
    const float* __restrict__ partials, int n, float* __restrict__ out)
{
    int tid = threadIdx.x;
    double s = 0.0;
    for (int i = tid; i < n; i += 256) s += (double)partials[i];
    #pragma unroll
    for (int o = 32; o > 0; o >>= 1) s += __shfl_down(s, o, 64);
    __shared__ double red[4];
    if ((tid & 63) == 0) red[tid >> 6] = s;
    __syncthreads();
    if (tid == 0) {
        double t = red[0] + red[1] + red[2] + red[3];
        const double ntot = (double)BATCH * (double)DEPTH * (double)H * (double)W;
        out[0] = (float)(t / ntot);
    }
}

extern "C" void kernel_launch(void* const* d_in, const int* in_sizes, int n_in,
                              void* d_out, int out_size, void* d_ws, size_t ws_size,
                              hipStream_t stream) {
    const float* pred = (const float*)d_in[0];
    const float* gt   = (const float*)d_in[1];
    const float* mask = (const float*)d_in[2];
    float* partials = (float*)d_ws;

    dim3 grid((W / TW) * (H / TH), DEPTH / DC, BATCH);   // 72 x 16 x 2 = 2304
    sobel_loss_part<<<grid, 256, 0, stream>>>(pred, gt, mask, partials);

    int nparts = grid.x * grid.y * grid.z;
    reduce_final<<<1, 256, 0, stream>>>(partials, nparts, (float*)d_out);
}